// Round 5
// baseline (98.341 us; speedup 1.0000x reference)
//
#include <hip/hip_runtime.h>

// QConv2d v9: two-kernel split. Evidence across v6b/v7/fill: write BW scales with
// resident waves (~0.78 GB/s/wave: 8w->1.6, 16w->4.2, 32w->6.2 TB/s). The fused
// design caps at 16 waves/CU (X[64] => >=108 VGPR => 4 waves/SIMD; 69.6KB LDS =>
// 2 blocks/CU), so the dominant 67MB output write runs at half rate. Split:
//   stage1 (1024 waves): producer pipeline per (batch,quad), W -> ws (16.8MB,
//     CACHED stores -> L2/L3 resident; layout lane-major so stores coalesce).
//   stage2 (2048x256, ~40 VGPR, no LDS, 32 waves/CU = fill-kernel shape): read W
//     float4s (cache-hot), 16 lin-combs, nontemporal 67MB write at fill rate.
// XCD locality: blockIdx = z*256 + b on both kernels -> batch b always on XCD b%8.
// Fallback: if ws_size < 16MiB, launch the known-good fused v8 kernel.

#define TPB 512

typedef float nfloat4 __attribute__((ext_vector_type(4)));

// ---------------- stage 1: W[b][quad] = (ux (x) uy) rho_q (ux (x) uy)^T ----------------
// one 64-lane wave per (batch, quad). blockIdx = quad*256 + b.
// ws layout: ws[((b*4+quad)*64 + (i*8+j))*64 + lane], lane=(pyp,qyp) after transpose
//   => element W[quad][row=i*8+pyp][col=j*8+qyp]. Each store instr = 256B coalesced.
__global__ __launch_bounds__(64) void qconv_stage1(
    const float* __restrict__ rho,   // [256][128][128]
    const float* __restrict__ ux,    // [8][8]
    const float* __restrict__ uy,    // [8][8]
    float* __restrict__ ws)          // [256][4][64][64]
{
    __shared__ alignas(16) float T[64][68];   // transpose scratch, 17.4 KB

    const int lane = threadIdx.x;
    const int b    = blockIdx.x & 255;
    const int quad = blockIdx.x >> 8;
    const int c1 = quad >> 1, c2 = quad & 1;
    const int px = lane >> 3, qx = lane & 7;

    const float* rb = rho + (size_t)b * 16384
                    + (size_t)((c1 << 6) + (px << 3)) * 128 + (c2 << 6) + (qx << 3);

    float X[64];
    // load X[py][qy]: 16 x b128
#pragma unroll
    for (int py = 0; py < 8; ++py) {
        float4 lo = *(const float4*)(rb + py * 128);
        float4 hi = *(const float4*)(rb + py * 128 + 4);
        X[py*8+0]=lo.x; X[py*8+1]=lo.y; X[py*8+2]=lo.z; X[py*8+3]=lo.w;
        X[py*8+4]=hi.x; X[py*8+5]=hi.y; X[py*8+6]=hi.z; X[py*8+7]=hi.w;
    }

    // Stage A: contract qy (row-local, in-place)
#pragma unroll
    for (int r = 0; r < 8; ++r) {
        float t[8];
#pragma unroll
        for (int j = 0; j < 8; ++j) {
            float a = 0.f;
#pragma unroll
            for (int k = 0; k < 8; ++k) a += uy[j*8+k] * X[r*8+k];
            t[j] = a;
        }
#pragma unroll
        for (int j = 0; j < 8; ++j) X[r*8+j] = t[j];
    }

    // Stage B: contract py (col-local, in-place)
#pragma unroll
    for (int cc = 0; cc < 8; ++cc) {
        float t[8];
#pragma unroll
        for (int i = 0; i < 8; ++i) {
            float a = 0.f;
#pragma unroll
            for (int k = 0; k < 8; ++k) a += uy[i*8+k] * X[k*8+cc];
            t[i] = a;
        }
#pragma unroll
        for (int i = 0; i < 8; ++i) X[i*8+cc] = t[i];
    }

    // wave-private 64x64 lane<->reg transpose via LDS, XOR-swizzled columns
    // (row stride 68 == 4 mod 32; swizzle spreads same-(lane&7) lanes across all
    // 8 bank quads -> conflict-free b128 reads; 16B alignment preserved).
#pragma unroll
    for (int e = 0; e < 64; ++e)
        T[e][lane ^ (((e >> 3) & 7) << 2)] = X[e];
    __asm__ volatile("s_waitcnt lgkmcnt(0)" ::: "memory");  // DS in-order per wave
    {
        const int sw = ((lane >> 3) & 7) << 2;
#pragma unroll
        for (int f4 = 0; f4 < 16; ++f4) {
            float4 v = *(const float4*)&T[lane][(f4 * 4) ^ sw];
            X[f4*4+0]=v.x; X[f4*4+1]=v.y; X[f4*4+2]=v.z; X[f4*4+3]=v.w;
        }
    }

    // Stage C: contract qx (row-local, in-place)
#pragma unroll
    for (int p = 0; p < 8; ++p) {
        float t[8];
#pragma unroll
        for (int j = 0; j < 8; ++j) {
            float a = 0.f;
#pragma unroll
            for (int k = 0; k < 8; ++k) a += ux[j*8+k] * X[p*8+k];
            t[j] = a;
        }
#pragma unroll
        for (int j = 0; j < 8; ++j) X[p*8+j] = t[j];
    }

    // Stage D: contract px, one output row i at a time; store row immediately.
    // CACHED stores (no nt): W stays L2/L3-resident for stage2.
    float* wbase = ws + ((size_t)(b * 4 + quad) * 64) * 64 + lane;
#pragma unroll
    for (int i = 0; i < 8; ++i) {
#pragma unroll
        for (int j = 0; j < 8; ++j) {
            float acc = 0.f;
#pragma unroll
            for (int k = 0; k < 8; ++k) acc += ux[i*8+k] * X[k*8+j];
            wbase[(size_t)(i*8 + j) * 64] = acc;
        }
    }
}

// ---------------- stage 2: out = sum_quad uc-coeffs * W[quad], streamed ----------------
// 2048 blocks x 256 threads (32 waves/CU, ~fill shape). blockIdx = z*256 + b.
// thread: q = tid&15 (float4 col group), csh = (tid>>4)&1, p = z*8 + (tid>>5).
__global__ __launch_bounds__(256, 8) void qconv_stage2(
    const float* __restrict__ ws,    // [256][4][64][64] stage-1 layout
    const float* __restrict__ uc,    // [4][4]
    float* __restrict__ out)         // [256][256][256]
{
    const int tid = threadIdx.x;
    const int b   = blockIdx.x & 255;
    const int z   = blockIdx.x >> 8;          // 0..7
    const int q   = tid & 15;
    const int csh = (tid >> 4) & 1;
    const int p   = z * 8 + (tid >> 5);       // 0..63

    float e0[4], e1[4];
#pragma unroll
    for (int c = 0; c < 4; ++c) { e0[c] = uc[c*4+2]; e1[c] = uc[c*4+3]; }

    // W[quad][p][4q..4q+3] at ws[(b*4+quad)*4096 + ((p>>3)*8+(q>>1))*64 + (p&7)*8 + (q&1)*4]
    const float* wb = ws + (size_t)b * 16384
                    + (size_t)(((p >> 3) * 8 + (q >> 1)) * 64 + (p & 7) * 8 + (q & 1) * 4);
    nfloat4 wv[4];
#pragma unroll
    for (int quad = 0; quad < 4; ++quad)
        wv[quad] = *(const nfloat4*)(wb + quad * 4096);

    float* ob = out + (size_t)b * 65536 + (size_t)p * 256 + q * 4;
#pragma unroll
    for (int c = 0; c < 4; ++c) {
#pragma unroll
        for (int cs2 = 0; cs2 < 2; ++cs2) {
            const int cs = 2 * csh + cs2;
            const float k00 = e0[c]*e0[cs], k01 = e0[c]*e1[cs];
            const float k10 = e1[c]*e0[cs], k11 = e1[c]*e1[cs];
            nfloat4 v;
            v.x = k00*wv[0].x + k01*wv[1].x + k10*wv[2].x + k11*wv[3].x;
            v.y = k00*wv[0].y + k01*wv[1].y + k10*wv[2].y + k11*wv[3].y;
            v.z = k00*wv[0].z + k01*wv[1].z + k10*wv[2].z + k11*wv[3].z;
            v.w = k00*wv[0].w + k01*wv[1].w + k10*wv[2].w + k11*wv[3].w;
            __builtin_nontemporal_store(v, (nfloat4*)(ob + c * 16384 + cs * 64));
        }
    }
}

// ---------------- fallback: known-good fused v8 (used only if ws too small) ----------------
__global__ __launch_bounds__(TPB, 2) void qconv_fused(
    const float* __restrict__ rho, const float* __restrict__ ux,
    const float* __restrict__ uy, const float* __restrict__ uc,
    float* __restrict__ out)
{
    __shared__ alignas(16) float L[4][64][68];

    const int tid  = threadIdx.x;
    const int bid  = blockIdx.x;
    const int b    = bid >> 1;
    const int h    = bid & 1;
    const int w    = tid >> 6;
    const int lane = tid & 63;
    const int pyp  = lane >> 3, qyp = lane & 7;

    const int qg  = tid & 15;
    const int csh = (tid >> 4) & 1;
    const int spl = tid >> 5;

    float e0[4], e1[4];
#pragma unroll
    for (int c = 0; c < 4; ++c) { e0[c] = uc[c*4+2]; e1[c] = uc[c*4+3]; }
    float* ob = out + (size_t)b * 65536;

    float X[64];

    if (w < 4) {
        const int c1 = w >> 1, c2 = w & 1;
        const int px = lane >> 3, qx = lane & 7;
        const float* rb = rho + (size_t)b * 16384
                        + (size_t)((c1 << 6) + (px << 3)) * 128 + (c2 << 6) + (qx << 3);
#pragma unroll
        for (int py = 0; py < 8; ++py) {
            float4 lo = *(const float4*)(rb + py * 128);
            float4 hi = *(const float4*)(rb + py * 128 + 4);
            X[py*8+0]=lo.x; X[py*8+1]=lo.y; X[py*8+2]=lo.z; X[py*8+3]=lo.w;
            X[py*8+4]=hi.x; X[py*8+5]=hi.y; X[py*8+6]=hi.z; X[py*8+7]=hi.w;
        }
#pragma unroll
        for (int r = 0; r < 8; ++r) {
            float t[8];
#pragma unroll
            for (int j = 0; j < 8; ++j) {
                float a = 0.f;
#pragma unroll
                for (int k = 0; k < 8; ++k) a += uy[j*8+k] * X[r*8+k];
                t[j] = a;
            }
#pragma unroll
            for (int j = 0; j < 8; ++j) X[r*8+j] = t[j];
        }
#pragma unroll
        for (int cc = 0; cc < 8; ++cc) {
            float t[8];
#pragma unroll
            for (int i = 0; i < 8; ++i) {
                float a = 0.f;
#pragma unroll
                for (int k = 0; k < 8; ++k) a += uy[i*8+k] * X[k*8+cc];
                t[i] = a;
            }
#pragma unroll
            for (int i = 0; i < 8; ++i) X[i*8+cc] = t[i];
        }
#pragma unroll
        for (int e = 0; e < 64; ++e)
            L[w][e][lane ^ (((e >> 3) & 7) << 2)] = X[e];
        __asm__ volatile("s_waitcnt lgkmcnt(0)" ::: "memory");
        {
            const int sw = ((lane >> 3) & 7) << 2;
#pragma unroll
            for (int f4 = 0; f4 < 16; ++f4) {
                float4 v = *(const float4*)&L[w][lane][(f4 * 4) ^ sw];
                X[f4*4+0]=v.x; X[f4*4+1]=v.y; X[f4*4+2]=v.z; X[f4*4+3]=v.w;
            }
        }
#pragma unroll
        for (int p = 0; p < 8; ++p) {
            float t[8];
#pragma unroll
            for (int j = 0; j < 8; ++j) {
                float a = 0.f;
#pragma unroll
                for (int k = 0; k < 8; ++k) a += ux[j*8+k] * X[p*8+k];
                t[j] = a;
            }
#pragma unroll
            for (int j = 0; j < 8; ++j) X[p*8+j] = t[j];
        }
    }

#pragma unroll
    for (int s2 = 0; s2 < 2; ++s2) {
        const int s = 2*h + s2;
        if (w < 4) {
#pragma unroll
            for (int i2 = 0; i2 < 2; ++i2) {
                const int i = 2*s + i2;
#pragma unroll
                for (int j = 0; j < 8; ++j) {
                    float acc = 0.f;
#pragma unroll
                    for (int k = 0; k < 8; ++k) acc += ux[i*8+k] * X[k*8+j];
                    L[w][i*8+pyp][j*8+qyp] = acc;
                }
            }
        }
        __asm__ volatile("s_waitcnt lgkmcnt(0)" ::: "memory");
        __builtin_amdgcn_s_barrier();
        __asm__ volatile("" ::: "memory");

        const int sp = 16*s + spl;
        float4 wv[4];
#pragma unroll
        for (int ww = 0; ww < 4; ++ww) wv[ww] = *(const float4*)&L[ww][sp][qg * 4];
#pragma unroll
        for (int c = 0; c < 4; ++c) {
#pragma unroll
            for (int cs2 = 0; cs2 < 2; ++cs2) {
                const int cs = 2*csh + cs2;
                const float k00 = e0[c]*e0[cs], k01 = e0[c]*e1[cs];
                const float k10 = e1[c]*e0[cs], k11 = e1[c]*e1[cs];
                nfloat4 v;
                v.x = k00*wv[0].x + k01*wv[1].x + k10*wv[2].x + k11*wv[3].x;
                v.y = k00*wv[0].y + k01*wv[1].y + k10*wv[2].y + k11*wv[3].y;
                v.z = k00*wv[0].z + k01*wv[1].z + k10*wv[2].z + k11*wv[3].z;
                v.w = k00*wv[0].w + k01*wv[1].w + k10*wv[2].w + k11*wv[3].w;
                __builtin_nontemporal_store(v,
                    (nfloat4*)&ob[(size_t)((c*64 + sp) * 256 + cs*64 + qg*4)]);
            }
        }
    }
}

extern "C" void kernel_launch(void* const* d_in, const int* in_sizes, int n_in,
                              void* d_out, int out_size, void* d_ws, size_t ws_size,
                              hipStream_t stream) {
    const float* rho = (const float*)d_in[0];
    const float* ux  = (const float*)d_in[1];
    const float* uy  = (const float*)d_in[2];
    const float* uc  = (const float*)d_in[3];
    float* out = (float*)d_out;

    const size_t ws_needed = (size_t)256 * 4 * 64 * 64 * sizeof(float);  // 16 MiB
    if (ws_size >= ws_needed && d_ws != nullptr) {
        float* ws = (float*)d_ws;
        qconv_stage1<<<dim3(1024), dim3(64),  0, stream>>>(rho, ux, uy, ws);
        qconv_stage2<<<dim3(2048), dim3(256), 0, stream>>>(ws, uc, out);
    } else {
        qconv_fused<<<dim3(512), dim3(TPB), 0, stream>>>(rho, ux, uy, uc, out);
    }
}